// Round 2
// baseline (2203.670 us; speedup 1.0000x reference)
//
#include <hip/hip_runtime.h>

// SineLSTM: 2-layer LSTM (H=50), B=512 independent rows, one row per block.
// R4 = R3 resubmit (previous bench was an infra failure, no kernel verdict).
// R3: readlane-broadcast restructure.
//   Old bottleneck: 150 scalar ds_read (h-broadcast) per thread-step => ~1200
//   LDS instrs/CU/step through one LDS pipe (~3000 cy) + 3 barriers.
//   New: layer states h1/c1/h2/c2 are REDUNDANT per wave (registers); the
//   h.W dot products broadcast h[k] via v_readlane -> SGPR feeding v_fma's
//   scalar operand (per-SIMD VALU, no LDS). Only the 200 gate values cross
//   waves, packed as float4 g[unit][i,f,g,o]: 1 ds_write + 1 ds_read_b128
//   per wave per layer. 2 barriers/step (gate exchange only).
//   Accumulation order / activation math kept bit-identical to the passing
//   baseline (absmax was near threshold).

#define Hh   50
#define G4   200      // 4*H
#define TLEN 1024     // teacher-forced sequence length (setup_inputs fixed)

__device__ __forceinline__ float fast_sigmoid(float v) {
    return 1.0f / (1.0f + __expf(-v));
}
__device__ __forceinline__ float fast_tanh(float v) {
    // 1 - 2/(e^{2v}+1); saturates correctly for |v| large
    return 1.0f - 2.0f / (__expf(2.0f * v) + 1.0f);
}
// wave-uniform broadcast of lane k's value through an SGPR (VALU pipe, not LDS)
__device__ __forceinline__ float rl(float v, int k) {
    return __int_as_float(__builtin_amdgcn_readlane(__float_as_int(v), k));
}

extern "C" __global__ __launch_bounds__(256, 2)
void sine_lstm_kernel(const float* __restrict__ x,
                      const float* __restrict__ W_ih1,
                      const float* __restrict__ W_hh1,
                      const float* __restrict__ b_ih1,
                      const float* __restrict__ b_hh1,
                      const float* __restrict__ W_ih2,
                      const float* __restrict__ W_hh2,
                      const float* __restrict__ b_ih2,
                      const float* __restrict__ b_hh2,
                      const float* __restrict__ W_lin,
                      const float* __restrict__ b_lin,
                      const int*   __restrict__ predict_p,
                      float* __restrict__ out,
                      int T)
{
    __shared__ __align__(16) float x_lds[TLEN];
    __shared__ __align__(16) float g1v[Hh][4];   // [unit][i,f,g,o]
    __shared__ __align__(16) float g2v[Hh][4];
    __shared__ float o_lds;

    const int tid = threadIdx.x;
    const int wv  = tid >> 6;              // wave id 0..3 = gate type (i,f,g,o)
    const int ln  = tid & 63;              // lane = unit id (ln<50 active)
    const int b   = blockIdx.x;            // one batch row per block
    const int predict = *predict_p;
    const int S = T + predict;

    // ---- stage x row into LDS (coalesced, once) ----
    for (int i = tid; i < TLEN; i += 256)
        x_lds[i] = x[(size_t)b * T + i];

    const bool act = (ln < Hh);
    const int  j   = wv * Hh + ln;         // gate row index: type wv, unit ln
    const int  jc  = act ? j : 0;          // clamp so inactive lanes load valid rows

    // ---- per-thread weight rows (register-resident for the whole loop) ----
    float w1[Hh], wi2[Hh], wh2[Hh];
    const float wih1_j = W_ih1[jc];
    const float b1_j   = b_ih1[jc] + b_hh1[jc];
    const float b2_j   = b_ih2[jc] + b_hh2[jc];
    #pragma unroll
    for (int k = 0; k < Hh; ++k) {
        w1[k]  = W_hh1[jc * Hh + k];
        wi2[k] = W_ih2[jc * Hh + k];
        wh2[k] = W_hh2[jc * Hh + k];
    }

    const float wlin_l = act ? W_lin[ln] : 0.0f;
    const float blin   = b_lin[0];

    // redundant per-wave state: lane l holds unit l's h/c (identical across waves)
    float h1r = 0.0f, c1r = 0.0f, h2r = 0.0f, c2r = 0.0f;

    __syncthreads();

    for (int s = 0; s < S; ++s) {
        float xin = (s < T) ? x_lds[s] : o_lds;

        // ======== G1: gate(wv,ln) = b1 + xin*W_ih1 + h1.W_hh1 (readlane bcast) ===
        {
            float a0 = b1_j + xin * wih1_j, a1 = 0.0f, a2 = 0.0f, a3 = 0.0f;
            #pragma unroll
            for (int k = 0; k < 48; k += 4) {
                a0 += w1[k]     * rl(h1r, k);
                a1 += w1[k + 1] * rl(h1r, k + 1);
                a2 += w1[k + 2] * rl(h1r, k + 2);
                a3 += w1[k + 3] * rl(h1r, k + 3);
            }
            a0 += w1[48] * rl(h1r, 48);
            a1 += w1[49] * rl(h1r, 49);
            if (act) g1v[ln][wv] = (a0 + a2) + (a1 + a3);
        }
        __syncthreads();   // B1: g1 complete
        //   (also orders U2(s-1)'s g2 reads before this step's G2 writes: the
        //    read is before B1(s) in program order, the write after.)

        // ======== U1: every wave redundantly updates layer-1 state (registers) ===
        if (act) {
            float4 g = *(const float4*)&g1v[ln][0];   // (i,f,g,o)
            float cn = fast_sigmoid(g.y) * c1r + fast_sigmoid(g.x) * fast_tanh(g.z);
            c1r = cn;
            h1r = fast_sigmoid(g.w) * fast_tanh(cn);
        }

        // ======== G2: gate(wv,ln) = b2 + h1.W_ih2 + h2.W_hh2 (readlane bcast) ===
        {
            float a0 = b2_j, a1 = 0.0f, a2 = 0.0f, a3 = 0.0f;
            #pragma unroll
            for (int k = 0; k < 48; k += 4) {
                a0 += wi2[k]     * rl(h1r, k);
                a1 += wi2[k + 1] * rl(h1r, k + 1);
                a2 += wi2[k + 2] * rl(h1r, k + 2);
                a3 += wi2[k + 3] * rl(h1r, k + 3);
            }
            a0 += wi2[48] * rl(h1r, 48);
            a1 += wi2[49] * rl(h1r, 49);
            #pragma unroll
            for (int k = 0; k < 48; k += 4) {
                a0 += wh2[k]     * rl(h2r, k);
                a1 += wh2[k + 1] * rl(h2r, k + 1);
                a2 += wh2[k + 2] * rl(h2r, k + 2);
                a3 += wh2[k + 3] * rl(h2r, k + 3);
            }
            a0 += wh2[48] * rl(h2r, 48);
            a1 += wh2[49] * rl(h2r, 49);
            if (act) g2v[ln][wv] = (a0 + a2) + (a1 + a3);
        }
        __syncthreads();   // B2: g2 complete
        //   (also orders U1(s)'s g1 reads before G1(s+1)'s writes.)

        // ======== U2: every wave redundantly updates layer-2 state =============
        if (act) {
            float4 g = *(const float4*)&g2v[ln][0];
            float cn = fast_sigmoid(g.y) * c2r + fast_sigmoid(g.x) * fast_tanh(g.z);
            c2r = cn;
            h2r = fast_sigmoid(g.w) * fast_tanh(cn);
        }

        // ======== OUT: round-robin wave does the h2.W_lin reduce ===============
        // (all waves hold identical h2; rotating the owner amortizes the ~90cy
        //  reduce skew to ~22cy/step at the next barrier)
        if (wv == (s & 3)) {
            float part = h2r * wlin_l;     // lanes >=50: h2r==0 and wlin_l==0
            #pragma unroll
            for (int off = 32; off > 0; off >>= 1)
                part += __shfl_down(part, off);
            if (ln == 0) {
                float o = part + blin;
                out[(size_t)b * S + s] = o;
                o_lds = o;                 // ordered vs readers by the s>=T-1 barrier
            }
        }
        // publish o_lds before it feeds next step's G1 (predict phase only)
        if (s >= T - 1) __syncthreads();
    }
}

extern "C" void kernel_launch(void* const* d_in, const int* in_sizes, int n_in,
                              void* d_out, int out_size, void* d_ws, size_t ws_size,
                              hipStream_t stream) {
    const float* x      = (const float*)d_in[0];
    const float* W_ih1  = (const float*)d_in[1];
    const float* W_hh1  = (const float*)d_in[2];
    const float* b_ih1  = (const float*)d_in[3];
    const float* b_hh1  = (const float*)d_in[4];
    const float* W_ih2  = (const float*)d_in[5];
    const float* W_hh2  = (const float*)d_in[6];
    const float* b_ih2  = (const float*)d_in[7];
    const float* b_hh2  = (const float*)d_in[8];
    const float* W_lin  = (const float*)d_in[9];
    const float* b_lin  = (const float*)d_in[10];
    const int*   pred   = (const int*)d_in[11];
    float* out = (float*)d_out;

    const int B = 512;                 // fixed by setup_inputs
    const int T = in_sizes[0] / B;     // 1024

    dim3 grid(B), block(256);
    hipLaunchKernelGGL(sine_lstm_kernel, grid, block, 0, stream,
                       x, W_ih1, W_hh1, b_ih1, b_hh1,
                       W_ih2, W_hh2, b_ih2, b_hh2,
                       W_lin, b_lin, pred, out, T);
}

// Round 3
// 1641.425 us; speedup vs baseline: 1.3425x; 1.3425x over previous
//
#include <hip/hip_runtime.h>

// SineLSTM: 2-layer LSTM (H=50), B=512 independent rows, one row per block.
// R5: revert to R2 structure (readlane experiment R3/R4 regressed: redundant
// U-compute + readlane->SGPR->VALU chains + [Hh][4] bank conflicts).
// Single change vs R2: h1/h2 broadcast reads vectorized to ds_read_b128
// (12x float4 + 1 tail-float4 per 50-dot) -> LDS-pipe instrs per wave-step
// drop ~158 -> ~45. Gates stay in flat [200] layout (stride-1 scalar gathers,
// conflict-free). c1 moved from LDS to wave0-private register.
// Accumulation order kept bit-identical to R2 (absmax at threshold).

#define Hh   50
#define G4   200      // 4*H
#define TLEN 1024     // teacher-forced sequence length (setup_inputs fixed)

__device__ __forceinline__ float fast_sigmoid(float v) {
    return 1.0f / (1.0f + __expf(-v));
}
__device__ __forceinline__ float fast_tanh(float v) {
    // 1 - 2/(e^{2v}+1); saturates correctly for |v| large
    return 1.0f - 2.0f / (__expf(2.0f * v) + 1.0f);
}

extern "C" __global__ __launch_bounds__(256, 2)
void sine_lstm_kernel(const float* __restrict__ x,
                      const float* __restrict__ W_ih1,
                      const float* __restrict__ W_hh1,
                      const float* __restrict__ b_ih1,
                      const float* __restrict__ b_hh1,
                      const float* __restrict__ W_ih2,
                      const float* __restrict__ W_hh2,
                      const float* __restrict__ b_ih2,
                      const float* __restrict__ b_hh2,
                      const float* __restrict__ W_lin,
                      const float* __restrict__ b_lin,
                      const int*   __restrict__ predict_p,
                      float* __restrict__ out,
                      int T)
{
    __shared__ __align__(16) float x_lds[TLEN];
    __shared__ __align__(16) float h1_lds[56];   // [50] + pad so float4@48 is in-bounds
    __shared__ __align__(16) float h2_lds[56];
    __shared__ __align__(16) float c2v[64];
    __shared__ __align__(16) float g1b[G4], g2b[G4];  // flat: gate*50+unit
    __shared__ float o_lds;

    const int tid = threadIdx.x;
    const int b   = blockIdx.x;            // one batch row per block
    const int predict = *predict_p;
    const int S = T + predict;

    // ---- stage x row into LDS (coalesced) ----
    for (int i = tid; i < TLEN; i += 256)
        x_lds[i] = x[(size_t)b * T + i];
    // ---- zero states (incl. float4 pad tails) ----
    if (tid < 56) { h1_lds[tid] = 0.0f; h2_lds[tid] = 0.0f; }
    if (tid < 64) c2v[tid] = 0.0f;

    // ---- per-thread weight rows (register/AGPR-resident for the whole loop) ----
    const int j = tid;
    float w1[Hh], wi2[Hh], wh2[Hh];
    float wih1_j = 0.0f, b1_j = 0.0f, b2_j = 0.0f;
    if (j < G4) {
        wih1_j = W_ih1[j];
        b1_j = b_ih1[j] + b_hh1[j];
        b2_j = b_ih2[j] + b_hh2[j];
        #pragma unroll
        for (int k = 0; k < Hh; ++k) {
            w1[k]  = W_hh1[j * Hh + k];
            wi2[k] = W_ih2[j * Hh + k];
            wh2[k] = W_hh2[j * Hh + k];
        }
    }

    const int wv = tid >> 6;               // wave id 0..3
    const int ln = tid & 63;               // lane
    const float wlin_l = (ln < Hh) ? W_lin[ln] : 0.0f;
    const float blin   = b_lin[0];
    float c1r = 0.0f;                      // layer-1 cell state: wave0-private

    __syncthreads();

    for (int s = 0; s < S; ++s) {
        // ======== G1: gates1[j] = b1 + xin*W_ih1[j] + h1·W_hh1[j] ========
        // h1 broadcast via ds_read_b128 (all lanes same addr, conflict-free)
        if (j < G4) {
            float xin = (s < T) ? x_lds[s] : o_lds;
            float a0 = b1_j + xin * wih1_j, a1 = 0.0f, a2 = 0.0f, a3 = 0.0f;
            #pragma unroll
            for (int k = 0; k < 48; k += 4) {
                float4 hv = *(const float4*)&h1_lds[k];
                a0 += w1[k]     * hv.x;
                a1 += w1[k + 1] * hv.y;
                a2 += w1[k + 2] * hv.z;
                a3 += w1[k + 3] * hv.w;
            }
            {
                float4 hv = *(const float4*)&h1_lds[48];   // pads unused
                a0 += w1[48] * hv.x;
                a1 += w1[49] * hv.y;
            }
            g1b[j] = (a0 + a2) + (a1 + a3);
        }
        __syncthreads();   // B1: g1 complete

        // ======== U1: wave0 lanes<50 update layer-1 state ========
        // (stride-1 gathers from flat g1b: conflict-free)
        if (wv == 0 && ln < Hh) {
            float ig = g1b[ln], fg = g1b[ln + Hh], gg = g1b[ln + 2 * Hh], og = g1b[ln + 3 * Hh];
            float cn = fast_sigmoid(fg) * c1r + fast_sigmoid(ig) * fast_tanh(gg);
            c1r = cn;
            h1_lds[ln] = fast_sigmoid(og) * fast_tanh(cn);
        }
        __syncthreads();   // B2: h1 complete

        // wave1 preloads c2 for its redundant U2 compute (c2 stable during G2)
        float cp2 = 0.0f;
        if (wv == 1 && ln < Hh) cp2 = c2v[ln];

        // ======== G2: gates2[j] = b2 + h1·W_ih2[j] + h2·W_hh2[j] ========
        if (j < G4) {
            float a0 = b2_j, a1 = 0.0f, a2 = 0.0f, a3 = 0.0f;
            #pragma unroll
            for (int k = 0; k < 48; k += 4) {
                float4 hv = *(const float4*)&h1_lds[k];
                a0 += wi2[k]     * hv.x;
                a1 += wi2[k + 1] * hv.y;
                a2 += wi2[k + 2] * hv.z;
                a3 += wi2[k + 3] * hv.w;
            }
            {
                float4 hv = *(const float4*)&h1_lds[48];
                a0 += wi2[48] * hv.x;
                a1 += wi2[49] * hv.y;
            }
            #pragma unroll
            for (int k = 0; k < 48; k += 4) {
                float4 hv = *(const float4*)&h2_lds[k];
                a0 += wh2[k]     * hv.x;
                a1 += wh2[k + 1] * hv.y;
                a2 += wh2[k + 2] * hv.z;
                a3 += wh2[k + 3] * hv.w;
            }
            {
                float4 hv = *(const float4*)&h2_lds[48];
                a0 += wh2[48] * hv.x;
                a1 += wh2[49] * hv.y;
            }
            g2b[j] = (a0 + a2) + (a1 + a3);
        }
        __syncthreads();   // B3: g2 complete

        // ======== U2a: wave0 = layer-2 state update ========
        if (wv == 0 && ln < Hh) {
            float ig = g2b[ln], fg = g2b[ln + Hh], gg = g2b[ln + 2 * Hh], og = g2b[ln + 3 * Hh];
            float c  = c2v[ln];
            float cn = fast_sigmoid(fg) * c + fast_sigmoid(ig) * fast_tanh(gg);
            c2v[ln] = cn;
            h2_lds[ln] = fast_sigmoid(og) * fast_tanh(cn);
        }
        // ======== U2b: wave1 = output dot (redundant activations) ========
        if (wv == 1) {
            float part = 0.0f;
            if (ln < Hh) {
                float ig = g2b[ln], fg = g2b[ln + Hh], gg = g2b[ln + 2 * Hh], og = g2b[ln + 3 * Hh];
                float cn = fast_sigmoid(fg) * cp2 + fast_sigmoid(ig) * fast_tanh(gg);
                float hn = fast_sigmoid(og) * fast_tanh(cn);
                part = hn * wlin_l;
            }
            #pragma unroll
            for (int off = 32; off > 0; off >>= 1)
                part += __shfl_down(part, off);
            if (ln == 0) {
                float o = part + blin;
                out[(size_t)b * S + s] = o;
                o_lds = o;
            }
        }
        // B4 only needed once o_lds feeds the next step's G1 (predict phase).
        // Hazard audit (same as R2): g1 writes(s+1) ordered after U1 reads(s)
        // by B2(s),B3(s); g2 writes(s+1) after U2 reads(s) by B1(s+1),B2(s+1);
        // h1 writes(s+1) after G2 reads(s) by B3(s)+B1(s+1); h2/c2 writes(s)
        // precede G2 reads(s+1) via B1(s+1)+B2(s+1).
        if (s >= T - 1) __syncthreads();
    }
}

extern "C" void kernel_launch(void* const* d_in, const int* in_sizes, int n_in,
                              void* d_out, int out_size, void* d_ws, size_t ws_size,
                              hipStream_t stream) {
    const float* x      = (const float*)d_in[0];
    const float* W_ih1  = (const float*)d_in[1];
    const float* W_hh1  = (const float*)d_in[2];
    const float* b_ih1  = (const float*)d_in[3];
    const float* b_hh1  = (const float*)d_in[4];
    const float* W_ih2  = (const float*)d_in[5];
    const float* W_hh2  = (const float*)d_in[6];
    const float* b_ih2  = (const float*)d_in[7];
    const float* b_hh2  = (const float*)d_in[8];
    const float* W_lin  = (const float*)d_in[9];
    const float* b_lin  = (const float*)d_in[10];
    const int*   pred   = (const int*)d_in[11];
    float* out = (float*)d_out;

    const int B = 512;                 // fixed by setup_inputs
    const int T = in_sizes[0] / B;     // 1024

    dim3 grid(B), block(256);
    hipLaunchKernelGGL(sine_lstm_kernel, grid, block, 0, stream,
                       x, W_ih1, W_hh1, b_ih1, b_hh1,
                       W_ih2, W_hh2, b_ih2, b_hh2,
                       W_lin, b_lin, pred, out, T);
}